// Round 6
// baseline (2846.934 us; speedup 1.0000x reference)
//
#include <hip/hip_runtime.h>

// ReservoirLayer: S0 = pad(x,[2048,4096]); 16x: S = leaky_relu(S @ W, 0.1)
// fp32-emulation via fp16 hi/lo split (fp16x3): acc = Sh@Wh + Sl@Wh + Sh@Wl.
// R3: depth-2 software pipeline (frags lead MFMAs by 1 iter, staging by 2).
// R5: 32x32x16 MFMA. R7/R8: conflict-free LDS reads via R3's proven wave
//     address pattern + pre-swizzled operand storage (staging = identity,
//     1KB contiguous per async16; conflicts = 0).
// R9: LDS-pipe load shedding. Evidence: R3/R6/R8 all ~175-190us regardless
//     of MFMA shape/conflicts; accounting says the CU LDS pipe (frag reads
//     128KB + staging writes 64KB per window) is the ~70%-busy long pole vs
//     MFMA ~50%. Since R8's storage format makes each B frag a coalesced
//     1KB global span identical to its LDS image, load B DIRECTLY
//     global->VGPR and delete sBh/sBl: LDS traffic per window halves
//     (96KB). Duplicate B reads across wm-wave pairs are served by CU L1
//     (16KB/window working set); W is read-only and LLC-resident.

#define BATCH 2048
#define NDIM  4096
#define INDIM 512
#define BM 128
#define BN 128
#define BK 32

typedef _Float16 f16x4  __attribute__((ext_vector_type(4)));
typedef _Float16 f16x8  __attribute__((ext_vector_type(8)));
typedef float    f32x16 __attribute__((ext_vector_type(16)));

__device__ __forceinline__ void async16(const void* gsrc, void* ldst) {
  const __attribute__((address_space(1))) unsigned int* g =
      (const __attribute__((address_space(1))) unsigned int*)gsrc;
  __attribute__((address_space(3))) unsigned int* l =
      (__attribute__((address_space(3))) unsigned int*)ldst;
  __builtin_amdgcn_global_load_lds(g, l, 16, 0, 0);
}

// inverse permutation: (rho, chunk-bit cb) -> slot l' within a region
__device__ __forceinline__ int slot_of(int rho, int cb) {
  int x = ((rho >> 4) & 1) | (cb << 1);
  return ((rho & 15) << 2) | (x ^ ((rho >> 1) & 3));
}

// ---------------- prep: split+pad x into swizzled S_hi/S_lo ----------------
__global__ void prep_x(const float* __restrict__ x,
                       _Float16* __restrict__ Sh, _Float16* __restrict__ Sl) {
  size_t i = (size_t)blockIdx.x * 256 + threadIdx.x;  // over BATCH*NDIM
  int b = (int)(i >> 12);
  int n = (int)(i & (NDIM - 1));
  float v = (n < INDIM) ? x[(size_t)b * INDIM + n] : 0.0f;
  _Float16 h = (_Float16)v;
  int rb = b >> 5, rho = b & 31;
  int kt = n >> 5, cn = n & 31;
  int chunk = cn >> 3, e = cn & 7;
  int s = chunk >> 1, cb = chunk & 1;
  int lp = slot_of(rho, cb);
  size_t a = ((((size_t)rb * 128 + kt) * 2 + s) << 9) + lp * 8 + e;
  Sh[a] = h;
  Sl[a] = (_Float16)(v - (float)h);
}

// ------- prep: transpose + scale(256) + split W into swizzled layout -------
__global__ void prep_w(const float* __restrict__ W,
                       _Float16* __restrict__ Wth, _Float16* __restrict__ Wtl) {
  __shared__ float tile[32][33];
  int nb = blockIdx.x, ktb = blockIdx.y;
  int k0 = ktb * 32, n0 = nb * 32;
  int tid = threadIdx.y * 32 + threadIdx.x;  // 32 x 8 = 256
  int tx = threadIdx.x, ty = threadIdx.y;
  for (int r = 0; r < 4; r++) {
    int k = ty + r * 8;
    tile[k][tx] = W[(size_t)(k0 + k) * NDIM + n0 + tx];  // tile[k_local][n_local]
  }
  __syncthreads();
  // write phase: t -> (s, slot l', half hh); 4 consecutive k-elems each
  int s = tid >> 7, lp = (tid >> 1) & 63, hh = tid & 1;
  int x = (lp & 3) ^ ((lp >> 3) & 3);
  int rho = (lp >> 2) + ((x & 1) << 4);   // n_local (B-row within block)
  int cb = x >> 1;
  int kbase = (2 * s + cb) * 8 + hh * 4;  // k_local of first of 4
  f16x4 hi4, lo4;
#pragma unroll
  for (int q = 0; q < 4; q++) {
    float v = tile[kbase + q][rho] * 256.0f;
    _Float16 h = (_Float16)v;
    hi4[q] = h;
    lo4[q] = (_Float16)(v - (float)h);
  }
  size_t base = ((((size_t)nb * 128 + ktb) * 2 + s) << 9) + lp * 8 + hh * 4;
  *(f16x4*)&Wth[base] = hi4;
  *(f16x4*)&Wtl[base] = lo4;
}

// read one frag set: A from LDS buffer b, B direct from global at k-tile kt
#define READF(b, kt, A, L, Bv, M)                          \
  do {                                                     \
    _Pragma("unroll") for (int i = 0; i < 2; i++)          \
    _Pragma("unroll") for (int s = 0; s < 2; s++) {        \
      A[i][s] = *(const f16x8*)&sAh[b][oA[i][s]];          \
      L[i][s] = *(const f16x8*)&sAl[b][oA[i][s]];          \
    }                                                      \
    _Pragma("unroll") for (int j = 0; j < 2; j++)          \
    _Pragma("unroll") for (int s = 0; s < 2; s++) {        \
      size_t gb = gB[j][s] + ((size_t)(kt) << 10);         \
      Bv[j][s] = *(const f16x8*)&Bh[gb];                   \
      M[j][s]  = *(const f16x8*)&Bl[gb];                   \
    }                                                      \
  } while (0)

// term-major order: consecutive MFMAs hit different accs (4-apart dep chain)
#define MFMAS(A, L, Bv, M)                                                                   \
  do {                                                                                       \
    _Pragma("unroll") for (int s = 0; s < 2; s++) {                                          \
      _Pragma("unroll") for (int j = 0; j < 2; j++)                                          \
      _Pragma("unroll") for (int i = 0; i < 2; i++)                                          \
        acc[i][j] = __builtin_amdgcn_mfma_f32_32x32x16_f16(A[i][s], Bv[j][s], acc[i][j], 0, 0, 0); \
      _Pragma("unroll") for (int j = 0; j < 2; j++)                                          \
      _Pragma("unroll") for (int i = 0; i < 2; i++)                                          \
        acc[i][j] = __builtin_amdgcn_mfma_f32_32x32x16_f16(L[i][s], Bv[j][s], acc[i][j], 0, 0, 0); \
      _Pragma("unroll") for (int j = 0; j < 2; j++)                                          \
      _Pragma("unroll") for (int i = 0; i < 2; i++)                                          \
        acc[i][j] = __builtin_amdgcn_mfma_f32_32x32x16_f16(A[i][s], M[j][s], acc[i][j], 0, 0, 0); \
    }                                                                                        \
  } while (0)

// ---------------- one recurrence step ----------------
template <int MODE>
__global__ __launch_bounds__(256, 2) void step_kernel(
    const _Float16* __restrict__ Ah, const _Float16* __restrict__ Al,
    const _Float16* __restrict__ Bh, const _Float16* __restrict__ Bl,
    _Float16* __restrict__ Dh, _Float16* __restrict__ Dl,
    float* __restrict__ Dout, int k_len) {
  // A only: 4 regions x 1KB per buffer (region (iblk*2+s) at (iblk*2+s)*512)
  __shared__ _Float16 sAh[2][BM * BK];
  __shared__ _Float16 sAl[2][BM * BK];

  const int tid = threadIdx.x;
  const int lane = tid & 63;
  const int w = tid >> 6;
  const int wm = w >> 1, wn = w & 1;

  // XCD-aware swizzle: 8x8 block region per XCD (round-robin dispatch, id&7)
  int id = blockIdx.x;
  int xcd = id & 7, local = id >> 3;
  int lr = local & 7, lc = local >> 3;
  const int bm = ((xcd & 1) * 8 + lr) * BM;
  const int bn = ((xcd >> 1) * 8 + lc) * BN;

  const int r31 = lane & 31;   // 32x32 frag row/col
  const int kh = lane >> 5;    // k-chunk select within the K=16 sub-frag

  // R3's proven-clean read pattern, single per-lane offset (elements):
  // byte(l) = (l&15)*64 + ((l>>4) ^ ((l>>1)&3))*16  within a 1KB region.
  const int lane_off = (lane & 15) * 32 + (((lane >> 4) ^ ((lane >> 1) & 3)) * 8);

  // A frag (i,s) reads LDS region (wm*2+i)*2+s
  int oA[2][2];
#pragma unroll
  for (int i = 0; i < 2; i++)
#pragma unroll
    for (int s = 0; s < 2; s++)
      oA[i][s] = (wm * 2 + i) * 1024 + s * 512 + lane_off;

  // B frag (j,s): direct global element base (add kt*1024 per tile).
  // Identical bytes/lane-mapping as the former LDS image -> same numerics.
  size_t gB[2][2];
#pragma unroll
  for (int j = 0; j < 2; j++)
#pragma unroll
    for (int s = 0; s < 2; s++)
      gB[j][s] = ((size_t)((bn >> 5) + wn * 2 + j) << 17) + s * 512 + lane_off;

  // A staging: operand pre-swizzled in memory -> identity copy. Wave w stages
  // row-block (bm/32 + w): 2 x 1KB fully-contiguous wave-linear spans / array.
  const size_t rbA = (size_t)((bm >> 5) + w) * 128;
  const int l8 = lane * 8;
  const int lo0 = w * 1024 + l8;  // LDS region 2w, lane-linear (elements)

  auto stage = [&](int ktI, int b) {
    const size_t rA = (rbA + ktI) << 10;  // element base of (rbA, ktI, s=0)
    async16(Ah + rA + l8,       &sAh[b][lo0]);
    async16(Ah + rA + 512 + l8, &sAh[b][lo0 + 512]);
    async16(Al + rA + l8,       &sAl[b][lo0]);
    async16(Al + rA + 512 + l8, &sAl[b][lo0 + 512]);
  };

  f32x16 acc[2][2];
#pragma unroll
  for (int i = 0; i < 2; i++)
#pragma unroll
    for (int j = 0; j < 2; j++)
#pragma unroll
      for (int e = 0; e < 16; e++) acc[i][j][e] = 0.0f;

  f16x8 a0[2][2], l0[2][2], b0[2][2], m0[2][2];  // frag set 0
  f16x8 a1[2][2], l1[2][2], b1[2][2], m1[2][2];  // frag set 1

  const int nk = k_len / BK;  // 16 or 128 (even)

  // prologue
  stage(0, 0);
  stage(1, 1);
  __syncthreads();               // A tiles 0,1 staged (one-time drain)
  READF(0, 0, a0, l0, b0, m0);
  __syncthreads();               // reads(0) drained -> buf0 reusable
  stage(2, 0);

  // main: READF(it) | MFMA(it-1) | sync | stage(it+2)
  int it = 1;
  for (; it + 1 < nk; it += 2) {
    READF(1, it, a1, l1, b1, m1);      // reads(it), it odd -> buf1
    MFMAS(a0, l0, b0, m0);             // MFMA(it-1)
    __syncthreads();
    if (it + 2 < nk) stage(it + 2, 1);

    READF(0, it + 1, a0, l0, b0, m0);  // reads(it+1), even -> buf0
    MFMAS(a1, l1, b1, m1);             // MFMA(it)
    __syncthreads();
    if (it + 3 < nk) stage(it + 3, 0);
  }
  // tail: it == nk-1 (odd)
  READF(1, nk - 1, a1, l1, b1, m1);    // reads(nk-1)
  MFMAS(a0, l0, b0, m0);               // MFMA(nk-2)
  MFMAS(a1, l1, b1, m1);               // MFMA(nk-1)

  // ---- epilogue: undo 256x W-scale, leaky relu, write next state / output
  // 32x32 C/D layout: col = lane&31, row = (reg&3) + 8*(reg>>2) + 4*(lane>>5)
  // MODE==0 writes the swizzled state format (inverse permutation slot_of).
  const float inv = 1.0f / 256.0f;
  const int chunk = r31 >> 3, ec = r31 & 7;
  const int s2 = chunk >> 1, cb = chunk & 1;
#pragma unroll
  for (int i = 0; i < 2; i++) {
#pragma unroll
    for (int j = 0; j < 2; j++) {
#pragma unroll
      for (int u = 0; u < 16; u++) {
        int rho = (u & 3) + 8 * (u >> 2) + 4 * kh;
        float g = acc[i][j][u] * inv;
        float s = (g > 0.0f) ? g : 0.1f * g;
        if (MODE == 0) {
          int rb = (bm >> 5) + wm * 2 + i;
          int ktn = (bn >> 5) + wn * 2 + j;
          int lp = slot_of(rho, cb);
          size_t a = ((((size_t)rb * 128 + ktn) * 2 + s2) << 9) + lp * 8 + ec;
          _Float16 h = (_Float16)s;
          Dh[a] = h;
          Dl[a] = (_Float16)(s - (float)h);
        } else {
          int r = bm + wm * 64 + i * 32 + rho;
          int c = bn + wn * 64 + j * 32 + r31;
          Dout[(size_t)r * NDIM + c] = s;
        }
      }
    }
  }
}

extern "C" void kernel_launch(void* const* d_in, const int* in_sizes, int n_in,
                              void* d_out, int out_size, void* d_ws, size_t ws_size,
                              hipStream_t stream) {
  const float* x = (const float*)d_in[0];  // [2048, 512]
  const float* W = (const float*)d_in[1];  // [4096, 4096]
  float* out = (float*)d_out;              // [2048, 4096]
  char* ws = (char*)d_ws;

  const size_t WT_BYTES = (size_t)NDIM * NDIM * 2;  // 32 MB each
  const size_t S_BYTES = (size_t)BATCH * NDIM * 2;  // 16 MB each
  _Float16* Wth = (_Float16*)ws;
  _Float16* Wtl = (_Float16*)(ws + WT_BYTES);
  _Float16* SAh = (_Float16*)(ws + 2 * WT_BYTES);
  _Float16* SAl = (_Float16*)(ws + 2 * WT_BYTES + S_BYTES);
  _Float16* SBh = (_Float16*)(ws + 2 * WT_BYTES + 2 * S_BYTES);
  _Float16* SBl = (_Float16*)(ws + 2 * WT_BYTES + 3 * S_BYTES);

  prep_x<<<(BATCH * NDIM) / 256, 256, 0, stream>>>(x, SAh, SAl);
  prep_w<<<dim3(NDIM / 32, NDIM / 32), dim3(32, 8), 0, stream>>>(W, Wth, Wtl);

  dim3 grid((NDIM / BN) * (BATCH / BM));  // 512 linear, swizzled in-kernel
  for (int t = 1; t <= 16; t++) {
    const _Float16* ah = (t & 1) ? SAh : SBh;
    const _Float16* al = (t & 1) ? SAl : SBl;
    _Float16* dh = (t & 1) ? SBh : SAh;
    _Float16* dl = (t & 1) ? SBl : SAl;
    int klen = (t == 1) ? INDIM : NDIM;
    if (t < 16)
      step_kernel<0><<<grid, 256, 0, stream>>>(ah, al, Wth, Wtl, dh, dl, nullptr, klen);
    else
      step_kernel<1><<<grid, 256, 0, stream>>>(ah, al, Wth, Wtl, nullptr, nullptr, out, klen);
  }
}

// Round 7
// 2407.958 us; speedup vs baseline: 1.1823x; 1.1823x over previous
//
#include <hip/hip_runtime.h>

// ReservoirLayer: S0 = pad(x,[2048,4096]); 16x: S = leaky_relu(S @ W, 0.1)
// fp32-emulation via fp16 hi/lo split (fp16x3): acc = Sh@Wh + Sl@Wh + Sh@Wl.
// R3 base (best measured: 175us/step, 0 conflicts, FETCH 131MB): depth-2
// software pipeline, 16x16x32 MFMA, XOR-chunk LDS layout.
// R10: counted-vmcnt raw-barrier schedule (T4). Evidence: R3/R6/R8/R9 all
//     plateau 175-209us with BOTH MFMA (~51%) and LDS (~50%) pipes half-idle
//     regardless of shape/conflicts/LDS-volume -> the 2-phase barrier drain
//     (s_waitcnt vmcnt(0) before every s_barrier) is the structural stall.
//     Replace __syncthreads with: read-barriers = s_waitcnt vmcnt(8) +
//     s_barrier (stage t+1's 8 loads stay in flight ACROSS the barrier);
//     overwrite-barriers = s_waitcnt lgkmcnt(0) + s_barrier (free: ds_reads
//     already retired feeding the MFMA block). vmcnt(0) only at tail.
//     sched_barrier(0) after each asm waitcnt (rule: hipcc hoists past asm).

#define BATCH 2048
#define NDIM  4096
#define INDIM 512
#define BM 128
#define BN 128
#define BK 32

typedef _Float16 f16x8 __attribute__((ext_vector_type(8)));
typedef float    f32x4 __attribute__((ext_vector_type(4)));

__device__ __forceinline__ void async16(const void* gsrc, void* ldst) {
  const __attribute__((address_space(1))) unsigned int* g =
      (const __attribute__((address_space(1))) unsigned int*)gsrc;
  __attribute__((address_space(3))) unsigned int* l =
      (__attribute__((address_space(3))) unsigned int*)ldst;
  __builtin_amdgcn_global_load_lds(g, l, 16, 0, 0);
}

#define WAITV8() do { asm volatile("s_waitcnt vmcnt(8)" ::: "memory"); \
                      __builtin_amdgcn_sched_barrier(0); } while (0)
#define WAITV0() do { asm volatile("s_waitcnt vmcnt(0)" ::: "memory"); \
                      __builtin_amdgcn_sched_barrier(0); } while (0)
#define LGKM0()  do { asm volatile("s_waitcnt lgkmcnt(0)" ::: "memory"); \
                      __builtin_amdgcn_sched_barrier(0); } while (0)
#define SBAR()   __builtin_amdgcn_s_barrier()

// ---------------- prep: split+pad x into S_hi/S_lo ----------------
__global__ void prep_x(const float* __restrict__ x,
                       _Float16* __restrict__ Sh, _Float16* __restrict__ Sl) {
  size_t i = (size_t)blockIdx.x * 256 + threadIdx.x;  // over BATCH*NDIM
  int b = (int)(i >> 12);
  int n = (int)(i & (NDIM - 1));
  float v = (n < INDIM) ? x[(size_t)b * INDIM + n] : 0.0f;
  _Float16 h = (_Float16)v;
  Sh[i] = h;
  Sl[i] = (_Float16)(v - (float)h);
}

// ---------------- prep: transpose + scale(256) + split W ----------------
__global__ void prep_w(const float* __restrict__ W,
                       _Float16* __restrict__ Wth, _Float16* __restrict__ Wtl) {
  __shared__ float tile[32][33];
  int k0 = blockIdx.y * 32, n0 = blockIdx.x * 32;
  int tx = threadIdx.x, ty = threadIdx.y;  // 32 x 8
  for (int r = 0; r < 4; r++) {
    int k = k0 + ty + r * 8;
    tile[ty + r * 8][tx] = W[(size_t)k * NDIM + n0 + tx];
  }
  __syncthreads();
  for (int r = 0; r < 4; r++) {
    int n = n0 + ty + r * 8;
    float v = tile[tx][ty + r * 8] * 256.0f;
    _Float16 h = (_Float16)v;
    Wth[(size_t)n * NDIM + k0 + tx] = h;
    Wtl[(size_t)n * NDIM + k0 + tx] = (_Float16)(v - (float)h);
  }
}

// read one frag set from LDS buffers b (compile-time 0/1 at all call sites)
#define READF(b, A, L, Bv, M)                          \
  do {                                                 \
    _Pragma("unroll") for (int i = 0; i < 4; i++) {    \
      A[i]  = *(const f16x8*)&sAh[b][oA[i]];           \
      L[i]  = *(const f16x8*)&sAl[b][oA[i]];           \
      Bv[i] = *(const f16x8*)&sBh[b][oB[i]];           \
      M[i]  = *(const f16x8*)&sBl[b][oB[i]];           \
    }                                                  \
  } while (0)

#define MFMAS(A, L, Bv, M)                                                          \
  do {                                                                              \
    _Pragma("unroll") for (int j = 0; j < 4; j++)                                   \
    _Pragma("unroll") for (int i = 0; i < 4; i++) {                                 \
      acc[i][j] = __builtin_amdgcn_mfma_f32_16x16x32_f16(A[i], Bv[j], acc[i][j], 0, 0, 0); \
      acc[i][j] = __builtin_amdgcn_mfma_f32_16x16x32_f16(L[i], Bv[j], acc[i][j], 0, 0, 0); \
      acc[i][j] = __builtin_amdgcn_mfma_f32_16x16x32_f16(A[i], M[j], acc[i][j], 0, 0, 0); \
    }                                                                               \
  } while (0)

// ---------------- one recurrence step ----------------
template <int MODE>
__global__ __launch_bounds__(256, 2) void step_kernel(
    const _Float16* __restrict__ Ah, const _Float16* __restrict__ Al,
    const _Float16* __restrict__ Bh, const _Float16* __restrict__ Bl,
    _Float16* __restrict__ Dh, _Float16* __restrict__ Dl,
    float* __restrict__ Dout, int k_len) {
  __shared__ _Float16 sAh[2][BM * BK];
  __shared__ _Float16 sAl[2][BM * BK];
  __shared__ _Float16 sBh[2][BN * BK];
  __shared__ _Float16 sBl[2][BN * BK];

  const int tid = threadIdx.x;
  const int lane = tid & 63;
  const int w = tid >> 6;
  const int wm = w >> 1, wn = w & 1;

  // XCD-aware swizzle: 8x8 block region per XCD (round-robin dispatch, id&7)
  int id = blockIdx.x;
  int xcd = id & 7, local = id >> 3;
  int lr = local & 7, lc = local >> 3;
  const int bm = ((xcd & 1) * 8 + lr) * BM;
  const int bn = ((xcd >> 1) * 8 + lc) * BN;

  const int sr = lane >> 2, cl = lane & 3;
  const int fm = lane & 15, fq = lane >> 4;

  // loop-invariant LDS fragment element-offsets (k-chunk swizzled)
  int oA[4], oB[4];
#pragma unroll
  for (int i = 0; i < 4; i++) {
    int rA = wm * 64 + i * 16 + fm;
    oA[i] = rA * BK + (fq ^ ((rA >> 1) & 3)) * 8;
    int rB = wn * 64 + i * 16 + fm;
    oB[i] = rB * BK + (fq ^ ((rB >> 1) & 3)) * 8;
  }

  // loop-invariant staging addresses (k added per call)
  int r0 = w * 32 + sr, r1 = r0 + 16;
  int cg0 = cl ^ ((r0 >> 1) & 3);
  int cg1 = cl ^ ((r1 >> 1) & 3);
  const size_t gA0 = (size_t)(bm + r0) * NDIM + cg0 * 8;
  const size_t gA1 = (size_t)(bm + r1) * NDIM + cg1 * 8;
  const size_t gB0 = (size_t)(bn + r0) * NDIM + cg0 * 8;
  const size_t gB1 = (size_t)(bn + r1) * NDIM + cg1 * 8;
  const int lo0 = r0 * BK + cl * 8;
  const int lo1 = r1 * BK + cl * 8;

  auto stage = [&](int kt, int b) {   // 8 global_load_lds per wave
    async16(Ah + gA0 + kt, &sAh[b][lo0]);
    async16(Ah + gA1 + kt, &sAh[b][lo1]);
    async16(Al + gA0 + kt, &sAl[b][lo0]);
    async16(Al + gA1 + kt, &sAl[b][lo1]);
    async16(Bh + gB0 + kt, &sBh[b][lo0]);
    async16(Bh + gB1 + kt, &sBh[b][lo1]);
    async16(Bl + gB0 + kt, &sBl[b][lo0]);
    async16(Bl + gB1 + kt, &sBl[b][lo1]);
  };

  f32x4 acc[4][4];
#pragma unroll
  for (int i = 0; i < 4; i++)
#pragma unroll
    for (int j = 0; j < 4; j++) acc[i][j] = (f32x4){0.f, 0.f, 0.f, 0.f};

  f16x8 a0[4], l0[4], b0[4], m0[4];  // frag set 0
  f16x8 a1[4], l1[4], b1[4], m1[4];  // frag set 1

  const int nk = k_len / BK;  // 16 or 128 (even)

  // prologue: issue tiles 0,1; wait only for tile 0 (oldest 8 of 16)
  stage(0 * BK, 0);
  stage(1 * BK, 1);
  WAITV8(); SBAR();              // stage(0) done, all waves
  READF(0, a0, l0, b0, m0);
  LGKM0(); SBAR();               // all waves' buf0 reads retired
  stage(2 * BK, 0);              // in flight: stage(1)+stage(2) = 16

  // main: WAITV8|SBAR -> READF(it) | MFMA(it-1) -> LGKM0|SBAR -> stage(it+2)
  int it = 1;
  for (; it + 1 < nk; it += 2) {
    WAITV8(); SBAR();            // stage(it) done (oldest 8 retired)
    READF(1, a1, l1, b1, m1);    // reads(it), it odd -> buf1
    MFMAS(a0, l0, b0, m0);       // MFMA(it-1)
    LGKM0(); SBAR();             // buf1 reads retired everywhere
    if (it + 2 < nk) stage((it + 2) * BK, 1);

    WAITV8(); SBAR();            // stage(it+1) done
    READF(0, a0, l0, b0, m0);    // reads(it+1), even -> buf0
    MFMAS(a1, l1, b1, m1);       // MFMA(it)
    LGKM0(); SBAR();             // buf0 reads retired everywhere
    if (it + 3 < nk) stage((it + 3) * BK, 0);
  }
  // tail: it == nk-1 (odd); only stage(nk-1) can still be in flight
  WAITV0(); SBAR();              // stage(nk-1) done, all waves
  READF(1, a1, l1, b1, m1);      // reads(nk-1)
  MFMAS(a0, l0, b0, m0);         // MFMA(nk-2)
  LGKM0();                       // reads(nk-1) retired (own-wave only needed)
  MFMAS(a1, l1, b1, m1);         // MFMA(nk-1)

  // ---- epilogue: undo 256x W-scale, leaky relu, write next state / output
  const float inv = 1.0f / 256.0f;
#pragma unroll
  for (int i = 0; i < 4; i++) {
#pragma unroll
    for (int j = 0; j < 4; j++) {
#pragma unroll
      for (int e = 0; e < 4; e++) {
        int r = bm + wm * 64 + i * 16 + fq * 4 + e;  // C/D: row=(lane>>4)*4+reg
        int c = bn + wn * 64 + j * 16 + fm;          //      col=lane&15
        float g = acc[i][j][e] * inv;
        float s = (g > 0.0f) ? g : 0.1f * g;
        if (MODE == 0) {
          _Float16 h = (_Float16)s;
          Dh[(size_t)r * NDIM + c] = h;
          Dl[(size_t)r * NDIM + c] = (_Float16)(s - (float)h);
        } else {
          Dout[(size_t)r * NDIM + c] = s;
        }
      }
    }
  }
}

extern "C" void kernel_launch(void* const* d_in, const int* in_sizes, int n_in,
                              void* d_out, int out_size, void* d_ws, size_t ws_size,
                              hipStream_t stream) {
  const float* x = (const float*)d_in[0];  // [2048, 512]
  const float* W = (const float*)d_in[1];  // [4096, 4096]
  float* out = (float*)d_out;              // [2048, 4096]
  char* ws = (char*)d_ws;

  const size_t WT_BYTES = (size_t)NDIM * NDIM * 2;  // 32 MB each
  const size_t S_BYTES = (size_t)BATCH * NDIM * 2;  // 16 MB each
  _Float16* Wth = (_Float16*)ws;
  _Float16* Wtl = (_Float16*)(ws + WT_BYTES);
  _Float16* SAh = (_Float16*)(ws + 2 * WT_BYTES);
  _Float16* SAl = (_Float16*)(ws + 2 * WT_BYTES + S_BYTES);
  _Float16* SBh = (_Float16*)(ws + 2 * WT_BYTES + 2 * S_BYTES);
  _Float16* SBl = (_Float16*)(ws + 2 * WT_BYTES + 3 * S_BYTES);

  prep_x<<<(BATCH * NDIM) / 256, 256, 0, stream>>>(x, SAh, SAl);
  prep_w<<<dim3(NDIM / 32, NDIM / 32), dim3(32, 8), 0, stream>>>(W, Wth, Wtl);

  dim3 grid((NDIM / BN) * (BATCH / BM));  // 512 linear, swizzled in-kernel
  for (int t = 1; t <= 16; t++) {
    const _Float16* ah = (t & 1) ? SAh : SBh;
    const _Float16* al = (t & 1) ? SAl : SBl;
    _Float16* dh = (t & 1) ? SBh : SAh;
    _Float16* dl = (t & 1) ? SBl : SAl;
    int klen = (t == 1) ? INDIM : NDIM;
    if (t < 16)
      step_kernel<0><<<grid, 256, 0, stream>>>(ah, al, Wth, Wtl, dh, dl, nullptr, klen);
    else
      step_kernel<1><<<grid, 256, 0, stream>>>(ah, al, Wth, Wtl, nullptr, nullptr, out, klen);
  }
}